// Round 2
// baseline (572.570 us; speedup 1.0000x reference)
//
#include <hip/hip_runtime.h>
#include <hip/hip_fp16.h>
#include <cmath>

// B=2, H=8, S=4096, d=64; fp32 in/out.
// e = (Q@K)/sqrt(512); a = softmax over HEADS; o = a@V.
//
// R9 = R8 (barrier-free register-softmax) with two fixes:
//  1. reduce_partials output index: raw [B,H,S,d] contiguous order (torch .view
//     semantics), NOT [B,S,H,d]. This was R8's sole correctness bug.
//  2. Q fragments live in wave-private LDS (padded stride 72 -> conflict-free
//     ds_read_b128), freeing 64 VGPRs: persistent set 160 (acc 128 + pf 32),
//     fits __launch_bounds__(256,2)'s 256-VGPR cap without spills.
//
// Structure recap:
//  - wave owns 16 s-rows x ALL 8 heads x t-chunk (TSPLIT=4 -> 1024 keys).
//  - swapped QK^T: mfma(kf, qf) -> lane holds scores at fixed (s=l15, t) for
//    every head -> head-softmax is lane-local (no LDS traffic, no barriers).
//  - kperm row permutation on the K A-frag makes score slot (quad, ts*4+r)
//    equal t = t0 + 8*quad + (ts*4+r), i.e. EXACTLY the 16x16x32 A-frag
//    k-layout, so normalized bf16 P feeds PV's A operand with zero movement.
//  - PV unswapped: mfma(pf, vf) -> acc[s=s0+4q+r][d=df*16+l15]; s-pairs pack
//    to bf16 u32 partials [c8][h][sp2048][d64], coalesced both sides.
//  - grid 512 blocks x 256 thr: combo(b,tc)=blockIdx&7 pins each (b,tc) to one
//    XCD (2MB K/V slice resident in 4MB L2); 2 blocks/CU, zero tail.
#define S_LEN 4096
#define NHEAD 8
#define HEADD 64
#define BN 32
#define TSPLIT 4
#define TCHUNK (S_LEN / TSPLIT)      // 1024 keys per combo
#define NTILE (TCHUNK / BN)          // 32 iterations
#define KPRE 0.0637588696f           // (1/sqrt(512)) * log2(e)

#define KT_BYTES (2ull * NHEAD * S_LEN * HEADD * 2)       // 8,388,608 bf16 K^T [t][k]
#define VT_OFF   KT_BYTES
#define PART_OFF (2 * KT_BYTES)                            // 16,777,216
#define PART_BYTES (8ull * NHEAD * (S_LEN / 2) * HEADD * 4) // 33,554,432 (8 combos)
#define WS_FULL  (PART_OFF + PART_BYTES)                   // 50,331,648

typedef __attribute__((ext_vector_type(8))) short   short8;
typedef __attribute__((ext_vector_type(4))) float   float4v;

__device__ __forceinline__ unsigned short f2bf(float f) {  // fp32 -> bf16 RNE
  unsigned int u = __float_as_uint(f);
  u += 0x7FFFu + ((u >> 16) & 1u);
  return (unsigned short)(u >> 16);
}

__device__ __forceinline__ unsigned int pkbf(float lo, float hi) {  // 2xfp32 -> packed bf16
  return __builtin_amdgcn_perm(__float_as_uint(hi) + 0x8000u,
                               __float_as_uint(lo) + 0x8000u, 0x07060302u);
}

// ---------------- pre-pass: LDS-free, float4 reads, in-register 8x4 transpose,
// b128 global writes. 1024 blocks x 256 thr (512 K-blocks, 512 V-blocks).
// K [bh,64,4096] f32 -> Kt [bh,4096,64] bf16*KPRE ; V [bh,4096,64] f32 -> Vt [bh,64,4096] bf16
__global__ __launch_bounds__(256)
void prepass_cvt(const float* __restrict__ K, const float* __restrict__ V,
                 unsigned short* __restrict__ Kt, unsigned short* __restrict__ Vt) {
  const int tid  = threadIdx.x;
  const int wave = tid >> 6, lane = tid & 63;
  const int isV  = blockIdx.x >> 9;
  const int idx  = blockIdx.x & 511;
  const int bh   = idx >> 5;                       // 16 bh
  const int t0   = (idx & 31) * 128 + wave * 32;   // block covers 128 t; wave covers 32 t
  if (!isV) {
    const float* in = K + (size_t)bh * HEADD * S_LEN;       // [k][t]
    unsigned short* out = Kt + (size_t)bh * S_LEN * HEADD;  // [t][k]
    const int koct = lane >> 3;          // k = koct*8 + j
    const int kt4  = (lane & 7) * 4;     // 4 t per lane
    float buf[8][4];
#pragma unroll
    for (int j = 0; j < 8; ++j) {
      float4v v = *(const float4v*)(in + (size_t)(koct * 8 + j) * S_LEN + t0 + kt4);
      buf[j][0] = v[0]; buf[j][1] = v[1]; buf[j][2] = v[2]; buf[j][3] = v[3];
    }
#pragma unroll
    for (int c = 0; c < 4; ++c) {
      short8 f;
#pragma unroll
      for (int j = 0; j < 8; ++j) f[j] = (short)f2bf(buf[j][c] * KPRE);
      *(short8*)(out + (size_t)(t0 + kt4 + c) * HEADD + koct * 8) = f;
    }
  } else {
    const float* in = V + (size_t)bh * S_LEN * HEADD;       // [t][d]
    unsigned short* out = Vt + (size_t)bh * HEADD * S_LEN;  // [d][t]
    const int vdq = lane & 15;           // d = vdq*4 + c
    const int vtg = lane >> 4;           // t = t0 + vtg*8 + j
    float buf[8][4];
#pragma unroll
    for (int j = 0; j < 8; ++j) {
      float4v v = *(const float4v*)(in + (size_t)(t0 + vtg * 8 + j) * HEADD + vdq * 4);
      buf[j][0] = v[0]; buf[j][1] = v[1]; buf[j][2] = v[2]; buf[j][3] = v[3];
    }
#pragma unroll
    for (int c = 0; c < 4; ++c) {
      short8 f;
#pragma unroll
      for (int j = 0; j < 8; ++j) f[j] = (short)f2bf(buf[j][c]);
      *(short8*)(out + (size_t)(vdq * 4 + c) * S_LEN + t0 + vtg * 8) = f;
    }
  }
}

// ---------------- main: 512 blocks x 256 thr (4 indep waves; no barriers).
// wave: 16 s-rows (s0..s0+15) x 8 heads x TCHUNK keys. 2 waves/SIMD.
__global__ __launch_bounds__(256, 2)
void attn_main(const float* __restrict__ Q, const unsigned short* __restrict__ Kt,
               const unsigned short* __restrict__ Vt, unsigned int* __restrict__ part) {
  // wave-private hoisted Q fragments; stride 72 shorts (144B): ds_read_b128
  // start bank = 4*(l15+quad) mod 32 -> uniform 32-bank coverage, no conflicts.
  __shared__ __align__(16) unsigned short Qs[4][NHEAD][16][72];   // 73,728 B

  const int tid   = threadIdx.x;
  const int w     = tid >> 6;
  const int lane  = tid & 63;
  const int quad  = lane >> 4;
  const int l15   = lane & 15;
  const int combo = blockIdx.x & 7;            // XCD-pinned (b,tc)
  const int b     = combo & 1;
  const int tc    = combo >> 1;
  const int s0    = (blockIdx.x >> 3) * 64 + w * 16;
  const int tbase = tc * TCHUNK;
  // A-frag m-row -> K-row offset so score slot (quad, ts*4+r) holds t = 8*quad + (ts*4+r)
  const int kperm = ((l15 >> 2) << 3) + (l15 & 3);

  // Q -> LDS (bf16, frag addressing: row=l15, col=kk*32+quad*8). Wave-private,
  // no __syncthreads needed; compiler orders ds_write->ds_read via lgkmcnt.
#pragma unroll
  for (int h = 0; h < NHEAD; ++h) {
    const float* Qg = Q + ((size_t)(b * NHEAD + h) * S_LEN + s0 + l15) * HEADD + quad * 8;
#pragma unroll
    for (int kk = 0; kk < 2; ++kk) {
      float4v a0 = *(const float4v*)(Qg + kk * 32);
      float4v a1 = *(const float4v*)(Qg + kk * 32 + 4);
      short8 f;
      f[0] = (short)f2bf(a0[0]); f[1] = (short)f2bf(a0[1]);
      f[2] = (short)f2bf(a0[2]); f[3] = (short)f2bf(a0[3]);
      f[4] = (short)f2bf(a1[0]); f[5] = (short)f2bf(a1[1]);
      f[6] = (short)f2bf(a1[2]); f[7] = (short)f2bf(a1[3]);
      *(short8*)&Qs[w][h][l15][kk * 32 + quad * 8] = f;
    }
  }

  // acc[h][df] = o[s = s0 + quad*4 + r][d = df*16 + l15]
  float4v acc[NHEAD][4];
#pragma unroll
  for (int h = 0; h < NHEAD; ++h)
#pragma unroll
    for (int df = 0; df < 4; ++df)
      acc[h][df] = (float4v){0.f, 0.f, 0.f, 0.f};

  const unsigned short* KtB = Kt + (size_t)b * NHEAD * S_LEN * HEADD;
  const unsigned short* VtB = Vt + (size_t)b * NHEAD * HEADD * S_LEN;

  for (int it = 0; it < NTILE; ++it) {
    const int t0 = tbase + it * BN;

    // ---- phase 1: swapped QK^T + exp2, all heads; sums in f32 (lane-local) ----
    short8 pf[NHEAD];            // bf16 exps; elem j at (t = t0 + 8*quad + j, s = s0+l15)
    float sum[8];
#pragma unroll
    for (int j = 0; j < 8; ++j) sum[j] = 0.f;
#pragma unroll
    for (int h = 0; h < NHEAD; ++h) {
      const unsigned short* Kth =
          KtB + ((size_t)h * S_LEN + (size_t)(t0 + kperm)) * HEADD + quad * 8;
      short8 k00 = *(const short8*)(Kth);                     // ts=0, kk=0
      short8 k01 = *(const short8*)(Kth + 32);                // ts=0, kk=1
      short8 k10 = *(const short8*)(Kth + 4 * HEADD);         // ts=1, kk=0
      short8 k11 = *(const short8*)(Kth + 4 * HEADD + 32);    // ts=1, kk=1
      short8 q0 = *(const short8*)&Qs[w][h][l15][quad * 8];
      short8 q1 = *(const short8*)&Qs[w][h][l15][32 + quad * 8];
      float4v e0 = (float4v){0.f, 0.f, 0.f, 0.f};
      float4v e1 = (float4v){0.f, 0.f, 0.f, 0.f};
      e0 = __builtin_amdgcn_mfma_f32_16x16x32_bf16(k00, q0, e0, 0, 0, 0);
      e0 = __builtin_amdgcn_mfma_f32_16x16x32_bf16(k01, q1, e0, 0, 0, 0);
      e1 = __builtin_amdgcn_mfma_f32_16x16x32_bf16(k10, q0, e1, 0, 0, 0);
      e1 = __builtin_amdgcn_mfma_f32_16x16x32_bf16(k11, q1, e1, 0, 0, 0);
      // K pre-scaled by scale*log2e -> scores are log2-domain
      float p0 = exp2f(e0[0]), p1 = exp2f(e0[1]), p2 = exp2f(e0[2]), p3 = exp2f(e0[3]);
      float p4 = exp2f(e1[0]), p5 = exp2f(e1[1]), p6 = exp2f(e1[2]), p7 = exp2f(e1[3]);
      sum[0] += p0; sum[1] += p1; sum[2] += p2; sum[3] += p3;
      sum[4] += p4; sum[5] += p5; sum[6] += p6; sum[7] += p7;
      unsigned int* u = (unsigned int*)&pf[h];
      u[0] = pkbf(p0, p1); u[1] = pkbf(p2, p3);
      u[2] = pkbf(p4, p5); u[3] = pkbf(p6, p7);
    }

    // ---- phase 2: per-slot inverse (8 rcp, lane-local) ----
    float inv[8];
#pragma unroll
    for (int j = 0; j < 8; ++j) inv[j] = __builtin_amdgcn_rcpf(sum[j]);

    // ---- phase 3: renormalize P in-register, then PV (unswapped) ----
#pragma unroll
    for (int h = 0; h < NHEAD; ++h) {
      unsigned int* u = (unsigned int*)&pf[h];
#pragma unroll
      for (int jr = 0; jr < 4; ++jr) {
        float lo = __uint_as_float(u[jr] << 16)         * inv[2 * jr];
        float hi = __uint_as_float(u[jr] & 0xffff0000u) * inv[2 * jr + 1];
        u[jr] = pkbf(lo, hi);
      }
      const unsigned short* Vth = VtB + (size_t)h * HEADD * S_LEN + t0 + quad * 8;
#pragma unroll
      for (int df = 0; df < 4; ++df) {
        short8 vf = *(const short8*)(Vth + (size_t)(df * 16 + l15) * S_LEN);
        acc[h][df] = __builtin_amdgcn_mfma_f32_16x16x32_bf16(pf[h], vf, acc[h][df], 0, 0, 0);
      }
    }
  }

  // ---- epilogue: bf16 s-pair partials, layout [c=tc*2+b][h][sp][d], coalesced ----
#pragma unroll
  for (int h = 0; h < NHEAD; ++h) {
    unsigned int* ph = part + (((size_t)combo * NHEAD + h) * (S_LEN / 2)
                               + (s0 >> 1) + quad * 2) * HEADD + l15;
#pragma unroll
    for (int df = 0; df < 4; ++df)
#pragma unroll
      for (int rp = 0; rp < 2; ++rp) {
        unsigned int ulo = __float_as_uint(acc[h][df][rp * 2])     + 0x8000u;
        unsigned int uhi = __float_as_uint(acc[h][df][rp * 2 + 1]) + 0x8000u;
        ph[(size_t)rp * HEADD + df * 16] = __builtin_amdgcn_perm(uhi, ulo, 0x07060302u);
      }
  }
}

// ---------------- reduce: sum 4 tc-partials (packed bf16 s-pairs) -> fp32 O ----------------
// part: [c=tc*2+b (8)][h (8)][sp (2048)][d (64)] u32. 8192 blocks x 256 thr.
// OUTPUT ORDER IS RAW [B,H,S,d] CONTIGUOUS (torch .view(B,S,512) is a reinterpret,
// NOT a head-transpose). R8's bug was writing [B,S,H,d] here.
__global__ __launch_bounds__(256)
void reduce_partials(const unsigned int* __restrict__ part, float* __restrict__ out) {
  const size_t tid = (size_t)blockIdx.x * 256 + threadIdx.x;   // 2,097,152 total
  const unsigned int d  = (unsigned int)(tid & 63);
  const unsigned int h  = (unsigned int)((tid >> 6) & 7);
  const unsigned int sp = (unsigned int)((tid >> 9) & 2047);
  const unsigned int b  = (unsigned int)(tid >> 20);
  float lo = 0.f, hi = 0.f;
#pragma unroll
  for (int tcc = 0; tcc < 4; ++tcc) {
    unsigned int v = part[(((size_t)(tcc * 2 + b) * NHEAD + h) * (S_LEN / 2) + sp) * HEADD + d];
    lo += __uint_as_float(v << 16);
    hi += __uint_as_float(v & 0xffff0000u);
  }
  float* o = out + (((size_t)(b * NHEAD + h)) * S_LEN + 2 * sp) * HEADD + d;
  o[0]     = lo;
  o[HEADD] = hi;   // s = 2*sp + 1
}

// ---------------- zero-workspace fallback (round-1 kernel, known correct) ----------------
__global__ __launch_bounds__(512, 2)
void attn_fallback(const float* __restrict__ Qg0, const float* __restrict__ Kg0,
                   const float* __restrict__ Vg0, float* __restrict__ Og0) {
  __shared__ __align__(16) unsigned short Klds[NHEAD][32][72];
  __shared__ __align__(16) unsigned short Vlds[NHEAD][HEADD][40];
  __shared__ __align__(16) unsigned short EA2[NHEAD][64][40];
  const int tid = threadIdx.x, h = tid >> 6, lane = tid & 63, quad = lane >> 4, l15 = lane & 15;
  const int b = blockIdx.x >> 6, s0 = (blockIdx.x & 63) * 64;
  const float* Qg = Qg0 + ((size_t)(b * NHEAD + h)) * S_LEN * HEADD;
  const float* Kg = Kg0 + ((size_t)(b * NHEAD + h)) * HEADD * S_LEN;
  const float* Vg = Vg0 + ((size_t)(b * NHEAD + h)) * S_LEN * HEADD;
  float* Og = Og0 + ((size_t)(b * NHEAD + h)) * S_LEN * HEADD;
  const float SC = 0.04419417382415922f;
  short8 qf[4][2];
#pragma unroll
  for (int ss = 0; ss < 4; ++ss)
#pragma unroll
    for (int kk = 0; kk < 2; ++kk) {
      const float* p = Qg + (size_t)(s0 + ss * 16 + l15) * HEADD + kk * 32 + quad * 8;
      float4v a0 = *(const float4v*)p; float4v a1 = *(const float4v*)(p + 4);
      short8 f;
      f[0] = (short)f2bf(a0[0]); f[1] = (short)f2bf(a0[1]); f[2] = (short)f2bf(a0[2]); f[3] = (short)f2bf(a0[3]);
      f[4] = (short)f2bf(a1[0]); f[5] = (short)f2bf(a1[1]); f[6] = (short)f2bf(a1[2]); f[7] = (short)f2bf(a1[3]);
      qf[ss][kk] = f;
    }
  float4v acc[4][4];
#pragma unroll
  for (int ss = 0; ss < 4; ++ss)
#pragma unroll
    for (int ds = 0; ds < 4; ++ds) acc[ss][ds] = (float4v){0.f, 0.f, 0.f, 0.f};
  const int koct = lane >> 3, kt4 = (lane & 7) * 4, vdq = lane & 15, vtg = lane >> 4;
  const int s_sm = tid >> 3, t4_sm = (tid & 7) * 4;
  for (int it = 0; it < S_LEN / 32; ++it) {
    const int t0 = it * 32;
    {
      float buf[8][4];
#pragma unroll
      for (int j = 0; j < 8; ++j) {
        float4v v = *(const float4v*)(Kg + (size_t)(koct * 8 + j) * S_LEN + t0 + kt4);
        buf[j][0] = v[0]; buf[j][1] = v[1]; buf[j][2] = v[2]; buf[j][3] = v[3];
      }
#pragma unroll
      for (int c = 0; c < 4; ++c) {
        short8 f;
#pragma unroll
        for (int j = 0; j < 8; ++j) f[j] = (short)f2bf(buf[j][c]);
        *(short8*)&Klds[h][kt4 + c][koct * 8] = f;
      }
    }
    {
      float buf[8][4];
#pragma unroll
      for (int j = 0; j < 8; ++j) {
        float4v v = *(const float4v*)(Vg + (size_t)(t0 + vtg * 8 + j) * HEADD + vdq * 4);
        buf[j][0] = v[0]; buf[j][1] = v[1]; buf[j][2] = v[2]; buf[j][3] = v[3];
      }
#pragma unroll
      for (int c = 0; c < 4; ++c) {
        short8 f;
#pragma unroll
        for (int j = 0; j < 8; ++j) f[j] = (short)f2bf(buf[j][c]);
        *(short8*)&Vlds[h][vdq * 4 + c][vtg * 8] = f;
      }
    }
    __syncthreads();
#pragma unroll
    for (int ts = 0; ts < 2; ++ts) {
      short8 kf0 = *(const short8*)&Klds[h][ts * 16 + l15][quad * 8];
      short8 kf1 = *(const short8*)&Klds[h][ts * 16 + l15][32 + quad * 8];
#pragma unroll
      for (int ss = 0; ss < 4; ++ss) {
        float4v e = (float4v){0.f, 0.f, 0.f, 0.f};
        e = __builtin_amdgcn_mfma_f32_16x16x32_bf16(qf[ss][0], kf0, e, 0, 0, 0);
        e = __builtin_amdgcn_mfma_f32_16x16x32_bf16(qf[ss][1], kf1, e, 0, 0, 0);
#pragma unroll
        for (int r = 0; r < 4; ++r)
          EA2[h][ss * 16 + quad * 4 + r][ts * 16 + l15] = __half_as_ushort(__float2half(e[r] * SC));
      }
    }
    __syncthreads();
    {
      float ev[8][4];
#pragma unroll
      for (int hh = 0; hh < 8; ++hh) {
        unsigned long long u = *(const unsigned long long*)&EA2[hh][s_sm][t4_sm];
        ev[hh][0] = __half2float(__ushort_as_half((unsigned short)u));
        ev[hh][1] = __half2float(__ushort_as_half((unsigned short)(u >> 16)));
        ev[hh][2] = __half2float(__ushort_as_half((unsigned short)(u >> 32)));
        ev[hh][3] = __half2float(__ushort_as_half((unsigned short)(u >> 48)));
      }
#pragma unroll
      for (int c = 0; c < 4; ++c) {
        float m = ev[0][c];
#pragma unroll
        for (int hh = 1; hh < 8; ++hh) m = fmaxf(m, ev[hh][c]);
        float sum = 0.f;
#pragma unroll
        for (int hh = 0; hh < 8; ++hh) { float x = __expf(ev[hh][c] - m); ev[hh][c] = x; sum += x; }
        float inv = __builtin_amdgcn_rcpf(sum);
#pragma unroll
        for (int hh = 0; hh < 8; ++hh) ev[hh][c] *= inv;
      }
#pragma unroll
      for (int hh = 0; hh < 8; ++hh) {
        unsigned short u0 = f2bf(ev[hh][0]), u1 = f2bf(ev[hh][1]), u2 = f2bf(ev[hh][2]), u3 = f2bf(ev[hh][3]);
        unsigned long long w = (unsigned long long)u0 | ((unsigned long long)u1 << 16) |
                               ((unsigned long long)u2 << 32) | ((unsigned long long)u3 << 48);
        *(unsigned long long*)&EA2[hh][s_sm][t4_sm] = w;
      }
    }
    __syncthreads();
    {
      short8 af[4], vf[4];
#pragma unroll
      for (int ss = 0; ss < 4; ++ss) af[ss] = *(const short8*)&EA2[h][ss * 16 + l15][quad * 8];
#pragma unroll
      for (int ds = 0; ds < 4; ++ds) vf[ds] = *(const short8*)&Vlds[h][ds * 16 + l15][quad * 8];
#pragma unroll
      for (int ss = 0; ss < 4; ++ss)
#pragma unroll
        for (int ds = 0; ds < 4; ++ds)
          acc[ss][ds] = __builtin_amdgcn_mfma_f32_16x16x32_bf16(af[ss], vf[ds], acc[ss][ds], 0, 0, 0);
    }
    __syncthreads();
  }
#pragma unroll
  for (int ss = 0; ss < 4; ++ss)
#pragma unroll
    for (int ds = 0; ds < 4; ++ds)
#pragma unroll
      for (int r = 0; r < 4; ++r)
        Og[(size_t)(s0 + ss * 16 + quad * 4 + r) * HEADD + ds * 16 + l15] = acc[ss][ds][r];
}

extern "C" void kernel_launch(void* const* d_in, const int* in_sizes, int n_in,
                              void* d_out, int out_size, void* d_ws, size_t ws_size,
                              hipStream_t stream) {
  const float* Q = (const float*)d_in[0];
  const float* K = (const float*)d_in[1];
  const float* V = (const float*)d_in[2];
  float* O = (float*)d_out;

  if (ws_size >= WS_FULL) {
    unsigned short* Kt = (unsigned short*)d_ws;
    unsigned short* Vt = (unsigned short*)((char*)d_ws + VT_OFF);
    unsigned int* part = (unsigned int*)((char*)d_ws + PART_OFF);
    hipLaunchKernelGGL(prepass_cvt, dim3(1024), dim3(256), 0, stream, K, V, Kt, Vt);
    hipLaunchKernelGGL(attn_main, dim3(512), dim3(256), 0, stream, Q, Kt, Vt, part);
    hipLaunchKernelGGL(reduce_partials, dim3(8192), dim3(256), 0, stream, part, O);
  } else {
    hipLaunchKernelGGL(attn_fallback, dim3(128), dim3(512), 0, stream, Q, K, V, O);
  }
}

// Round 3
// 356.296 us; speedup vs baseline: 1.6070x; 1.6070x over previous
//
#include <hip/hip_runtime.h>
#include <hip/hip_fp16.h>
#include <cmath>

// B=2, H=8, S=4096, d=64; fp32 in/out.
// e = (Q@K)/sqrt(512); a = softmax over HEADS; o = a@V.
//
// R10 = R7 (proven 278us attn_main structure: 512thr/8wave, wave=head, LDS
// cross-head softmax, 2 barriers/tile) + three targeted fixes:
//  1. TSPLIT 8->4: partials halve (67->33.5MB) -> attn_main writes halve,
//     reduce reads halve. Grid 1024 blocks, 8 XCD-pinned combos.
//  2. Merged phase A: {PV(it-1) || QK^T(it)} -> bar -> softmax(it) -> bar.
//     Same 2 barriers/tile, but all global loads + 12 MFMAs co-schedule in
//     one phase (loads issued first, hidden under the other matmul).
//     EA ping-pong gives 2 barriers between any conflicting access pair.
//  3. Softmax writes packed u32 (8 stores/thread instead of 16 u16).
// R8/R9 lesson: barrier-free register-softmax couples 8 heads in 128 acc
// VGPRs -> 2 waves/SIMD, serialized loads, 512us. LDS coupling wins.
#define S_LEN 4096
#define NHEAD 8
#define HEADD 64
#define BM 32
#define BN 32
#define TSPLIT 4
#define TCHUNK (S_LEN / TSPLIT)      // 1024 keys per combo
#define NTILE (TCHUNK / BN)          // 32 iterations
#define EAP 40                       // u16 pitch (R7-proven)
#define KPRE 0.0637588696f           // (1/sqrt(512)) * log2(e)

#define KT_BYTES (2ull * NHEAD * S_LEN * HEADD * 2)        // 8,388,608 bf16 K^T [t][k]
#define VT_OFF   KT_BYTES
#define PART_OFF (2 * KT_BYTES)                             // 16,777,216
#define PART_BYTES (8ull * NHEAD * (S_LEN / 2) * HEADD * 4) // 33,554,432 (8 combos)
#define WS_FULL  (PART_OFF + PART_BYTES)                    // 50,331,648

typedef __attribute__((ext_vector_type(8))) short   short8;
typedef __attribute__((ext_vector_type(4))) float   float4v;

__device__ __forceinline__ unsigned short f2bf(float f) {  // fp32 -> bf16 RNE
  unsigned int u = __float_as_uint(f);
  u += 0x7FFFu + ((u >> 16) & 1u);
  return (unsigned short)(u >> 16);
}

__device__ __forceinline__ unsigned int pkbf(float lo, float hi) {  // 2xfp32 -> packed bf16
  return __builtin_amdgcn_perm(__float_as_uint(hi) + 0x8000u,
                               __float_as_uint(lo) + 0x8000u, 0x07060302u);
}

// ---------------- pre-pass: LDS-free, float4 reads, in-register 8x4 transpose,
// b128 global writes. 1024 blocks x 256 thr (512 K-blocks, 512 V-blocks).
// K [bh,64,4096] f32 -> Kt [bh,4096,64] bf16*KPRE ; V [bh,4096,64] f32 -> Vt [bh,64,4096] bf16
__global__ __launch_bounds__(256)
void prepass_cvt(const float* __restrict__ K, const float* __restrict__ V,
                 unsigned short* __restrict__ Kt, unsigned short* __restrict__ Vt) {
  const int tid  = threadIdx.x;
  const int wave = tid >> 6, lane = tid & 63;
  const int isV  = blockIdx.x >> 9;
  const int idx  = blockIdx.x & 511;
  const int bh   = idx >> 5;                       // 16 bh
  const int t0   = (idx & 31) * 128 + wave * 32;   // block covers 128 t; wave covers 32 t
  if (!isV) {
    const float* in = K + (size_t)bh * HEADD * S_LEN;       // [k][t]
    unsigned short* out = Kt + (size_t)bh * S_LEN * HEADD;  // [t][k]
    const int koct = lane >> 3;          // k = koct*8 + j
    const int kt4  = (lane & 7) * 4;     // 4 t per lane
    float buf[8][4];
#pragma unroll
    for (int j = 0; j < 8; ++j) {
      float4v v = *(const float4v*)(in + (size_t)(koct * 8 + j) * S_LEN + t0 + kt4);
      buf[j][0] = v[0]; buf[j][1] = v[1]; buf[j][2] = v[2]; buf[j][3] = v[3];
    }
#pragma unroll
    for (int c = 0; c < 4; ++c) {
      short8 f;
#pragma unroll
      for (int j = 0; j < 8; ++j) f[j] = (short)f2bf(buf[j][c] * KPRE);
      *(short8*)(out + (size_t)(t0 + kt4 + c) * HEADD + koct * 8) = f;
    }
  } else {
    const float* in = V + (size_t)bh * S_LEN * HEADD;       // [t][d]
    unsigned short* out = Vt + (size_t)bh * HEADD * S_LEN;  // [d][t]
    const int vdq = lane & 15;           // d = vdq*4 + c
    const int vtg = lane >> 4;           // t = t0 + vtg*8 + j
    float buf[8][4];
#pragma unroll
    for (int j = 0; j < 8; ++j) {
      float4v v = *(const float4v*)(in + (size_t)(t0 + vtg * 8 + j) * HEADD + vdq * 4);
      buf[j][0] = v[0]; buf[j][1] = v[1]; buf[j][2] = v[2]; buf[j][3] = v[3];
    }
#pragma unroll
    for (int c = 0; c < 4; ++c) {
      short8 f;
#pragma unroll
      for (int j = 0; j < 8; ++j) f[j] = (short)f2bf(buf[j][c]);
      *(short8*)(out + (size_t)(vdq * 4 + c) * S_LEN + t0 + vtg * 8) = f;
    }
  }
}

// ---------------- main: 1024 blocks x 512 thr (8 waves, wave=head), BM=32 q-rows.
// combo = blockIdx&7: XCD-pinned (b,tc); each XCD's L2 holds its 2MB K/V slice.
__global__ __launch_bounds__(512, 6)
void attn_main(const float* __restrict__ Q, const unsigned short* __restrict__ Kt,
               const unsigned short* __restrict__ Vt, unsigned int* __restrict__ part) {
  __shared__ __align__(16) unsigned short EA[2][NHEAD][BM][EAP];  // 40,960 B

  const int tid  = threadIdx.x;
  const int h    = tid >> 6;
  const int lane = tid & 63;
  const int quad = lane >> 4;
  const int l15  = lane & 15;
  const int combo = blockIdx.x & 7;
  const int b  = combo & 1;
  const int tc = combo >> 1;
  const int s0 = (blockIdx.x >> 3) * BM;
  const int tbase = tc * TCHUNK;

  const float* Qg = Q + (size_t)(b * NHEAD + h) * S_LEN * HEADD;
  const unsigned short* Kth = Kt + (size_t)(b * NHEAD + h) * S_LEN * HEADD;  // [t][k]
  const unsigned short* Vth = Vt + (size_t)(b * NHEAD + h) * HEADD * S_LEN;  // [d][t]

  // Q fragments (A-layout 16x16x32: m=l15, k=quad*8+j)
  short8 qf[2][2];
#pragma unroll
  for (int ss = 0; ss < 2; ++ss)
#pragma unroll
    for (int kk = 0; kk < 2; ++kk) {
      const float* p = Qg + (size_t)(s0 + ss * 16 + l15) * HEADD + kk * 32 + quad * 8;
      float4v a0 = *(const float4v*)p;
      float4v a1 = *(const float4v*)(p + 4);
      short8 f;
      f[0] = (short)f2bf(a0[0]); f[1] = (short)f2bf(a0[1]);
      f[2] = (short)f2bf(a0[2]); f[3] = (short)f2bf(a0[3]);
      f[4] = (short)f2bf(a1[0]); f[5] = (short)f2bf(a1[1]);
      f[6] = (short)f2bf(a1[2]); f[7] = (short)f2bf(a1[3]);
      qf[ss][kk] = f;
    }

  float4v acc[2][4];
#pragma unroll
  for (int ss = 0; ss < 2; ++ss)
#pragma unroll
    for (int df = 0; df < 4; ++df)
      acc[ss][df] = (float4v){0.f, 0.f, 0.f, 0.f};

  const int s_sm = tid >> 4;        // 0..31
  const int tp   = tid & 15;        // t-pair index (t = 2*tp, 2*tp+1)

  // ---- prologue: QK^T(0) -> EA[0] ----
  {
    const int t0 = tbase;
    short8 kf[2][2];
#pragma unroll
    for (int ts = 0; ts < 2; ++ts)
#pragma unroll
      for (int kh = 0; kh < 2; ++kh)
        kf[ts][kh] = *(const short8*)(Kth + (size_t)(t0 + ts * 16 + l15) * HEADD + kh * 32 + quad * 8);
#pragma unroll
    for (int ss = 0; ss < 2; ++ss)
#pragma unroll
      for (int ts = 0; ts < 2; ++ts) {
        float4v e = (float4v){0.f, 0.f, 0.f, 0.f};
        e = __builtin_amdgcn_mfma_f32_16x16x32_bf16(qf[ss][0], kf[ts][0], e, 0, 0, 0);
        e = __builtin_amdgcn_mfma_f32_16x16x32_bf16(qf[ss][1], kf[ts][1], e, 0, 0, 0);
#pragma unroll
        for (int r = 0; r < 4; ++r)   // C/D: col=l15 (t), row=quad*4+r (s)
          EA[0][h][ss * 16 + quad * 4 + r][ts * 16 + l15] =
              __half_as_ushort(__float2half(e[r]));
      }
  }
  __syncthreads();
  // ---- softmax(0) ----
  {
    unsigned int x[8];
#pragma unroll
    for (int hh = 0; hh < 8; ++hh)
      x[hh] = *(const unsigned int*)&EA[0][hh][s_sm][tp * 2];
    float pl[8], ph[8];
    float sl = 0.f, sh = 0.f;
#pragma unroll
    for (int hh = 0; hh < 8; ++hh) {
      pl[hh] = exp2f(__half2float(__ushort_as_half((unsigned short)(x[hh] & 0xffffu))));
      ph[hh] = exp2f(__half2float(__ushort_as_half((unsigned short)(x[hh] >> 16))));
      sl += pl[hh]; sh += ph[hh];
    }
    float il = __builtin_amdgcn_rcpf(sl), ih = __builtin_amdgcn_rcpf(sh);
#pragma unroll
    for (int hh = 0; hh < 8; ++hh)
      *(unsigned int*)&EA[0][hh][s_sm][tp * 2] = pkbf(pl[hh] * il, ph[hh] * ih);
  }
  __syncthreads();

  // ---- main loop: phase A = {PV(it-1) || QK^T(it)}, phase B = softmax(it) ----
  for (int it = 1; it < NTILE; ++it) {
    const int t0 = tbase + it * BN;
    const int p  = it & 1;
    {
      // issue ALL global loads first (4 K b128 + 4 V b128), then LDS af reads;
      // PV MFMAs wait on V while K flies; QK^T MFMAs follow.
      short8 kf[2][2];
#pragma unroll
      for (int ts = 0; ts < 2; ++ts)
#pragma unroll
        for (int kh = 0; kh < 2; ++kh)
          kf[ts][kh] = *(const short8*)(Kth + (size_t)(t0 + ts * 16 + l15) * HEADD + kh * 32 + quad * 8);
      short8 vf[4];
#pragma unroll
      for (int df = 0; df < 4; ++df)
        vf[df] = *(const short8*)(Vth + (size_t)(df * 16 + l15) * S_LEN + (t0 - BN) + quad * 8);
      short8 af[2];
#pragma unroll
      for (int ss = 0; ss < 2; ++ss)
        af[ss] = *(const short8*)&EA[p ^ 1][h][ss * 16 + l15][quad * 8];
      // PV(it-1)
#pragma unroll
      for (int ss = 0; ss < 2; ++ss)
#pragma unroll
        for (int df = 0; df < 4; ++df)
          acc[ss][df] = __builtin_amdgcn_mfma_f32_16x16x32_bf16(af[ss], vf[df], acc[ss][df], 0, 0, 0);
      // QK^T(it)
#pragma unroll
      for (int ss = 0; ss < 2; ++ss)
#pragma unroll
        for (int ts = 0; ts < 2; ++ts) {
          float4v e = (float4v){0.f, 0.f, 0.f, 0.f};
          e = __builtin_amdgcn_mfma_f32_16x16x32_bf16(qf[ss][0], kf[ts][0], e, 0, 0, 0);
          e = __builtin_amdgcn_mfma_f32_16x16x32_bf16(qf[ss][1], kf[ts][1], e, 0, 0, 0);
#pragma unroll
          for (int r = 0; r < 4; ++r)
            EA[p][h][ss * 16 + quad * 4 + r][ts * 16 + l15] =
                __half_as_ushort(__float2half(e[r]));
        }
    }
    __syncthreads();
    // ---- softmax(it): 8 heads per (s, 2t) slot, packed u32 writeback ----
    {
      unsigned int x[8];
#pragma unroll
      for (int hh = 0; hh < 8; ++hh)
        x[hh] = *(const unsigned int*)&EA[p][hh][s_sm][tp * 2];
      float pl[8], ph[8];
      float sl = 0.f, sh = 0.f;
#pragma unroll
      for (int hh = 0; hh < 8; ++hh) {
        pl[hh] = exp2f(__half2float(__ushort_as_half((unsigned short)(x[hh] & 0xffffu))));
        ph[hh] = exp2f(__half2float(__ushort_as_half((unsigned short)(x[hh] >> 16))));
        sl += pl[hh]; sh += ph[hh];
      }
      float il = __builtin_amdgcn_rcpf(sl), ih = __builtin_amdgcn_rcpf(sh);
#pragma unroll
      for (int hh = 0; hh < 8; ++hh)
        *(unsigned int*)&EA[p][hh][s_sm][tp * 2] = pkbf(pl[hh] * il, ph[hh] * ih);
    }
    __syncthreads();
  }

  // ---- epilogue PV(NTILE-1) ----
  {
    const int t0 = tbase + (NTILE - 1) * BN;
    const int p  = (NTILE - 1) & 1;
    short8 vf[4];
#pragma unroll
    for (int df = 0; df < 4; ++df)
      vf[df] = *(const short8*)(Vth + (size_t)(df * 16 + l15) * S_LEN + t0 + quad * 8);
    short8 af[2];
#pragma unroll
    for (int ss = 0; ss < 2; ++ss)
      af[ss] = *(const short8*)&EA[p][h][ss * 16 + l15][quad * 8];
#pragma unroll
    for (int ss = 0; ss < 2; ++ss)
#pragma unroll
      for (int df = 0; df < 4; ++df)
        acc[ss][df] = __builtin_amdgcn_mfma_f32_16x16x32_bf16(af[ss], vf[df], acc[ss][df], 0, 0, 0);
  }

  // ---- partials: packed bf16 s-pairs, layout [combo(8)][h][sp(2048)][d(64)] ----
  unsigned int* pb = part + ((size_t)combo * NHEAD + h) * (2048ull * 64);
  const int spb = (s0 >> 1) + quad * 2;
#pragma unroll
  for (int ss = 0; ss < 2; ++ss)
#pragma unroll
    for (int df = 0; df < 4; ++df)
#pragma unroll
      for (int rp = 0; rp < 2; ++rp) {
        unsigned int ulo = __float_as_uint(acc[ss][df][rp * 2])     + 0x8000u;
        unsigned int uhi = __float_as_uint(acc[ss][df][rp * 2 + 1]) + 0x8000u;
        unsigned int pk  = __builtin_amdgcn_perm(uhi, ulo, 0x07060302u);
        pb[(size_t)(spb + ss * 8 + rp) * 64 + df * 16 + l15] = pk;
      }
}

// ---------------- reduce: sum 4 tc-partials (packed bf16 s-pairs) -> fp32 O ----------------
// part: [c=tc*2+b (8)][h (8)][sp (2048)][d (64)] u32. 8192 blocks x 256 thr.
// OUTPUT ORDER IS RAW [B,H,S,d] CONTIGUOUS (torch .view(B,S,512) is a reinterpret).
__global__ __launch_bounds__(256)
void reduce_partials(const unsigned int* __restrict__ part, float* __restrict__ out) {
  const size_t tid = (size_t)blockIdx.x * 256 + threadIdx.x;   // 2,097,152 total
  const unsigned int d  = (unsigned int)(tid & 63);
  const unsigned int h  = (unsigned int)((tid >> 6) & 7);
  const unsigned int sp = (unsigned int)((tid >> 9) & 2047);
  const unsigned int b  = (unsigned int)(tid >> 20);
  float lo = 0.f, hi = 0.f;
#pragma unroll
  for (int tcc = 0; tcc < 4; ++tcc) {
    unsigned int v = part[(((size_t)(tcc * 2 + b) * NHEAD + h) * (S_LEN / 2) + sp) * HEADD + d];
    lo += __uint_as_float(v << 16);
    hi += __uint_as_float(v & 0xffff0000u);
  }
  float* o = out + (((size_t)(b * NHEAD + h)) * S_LEN + 2 * sp) * HEADD + d;
  o[0]     = lo;
  o[HEADD] = hi;   // s = 2*sp + 1
}

// ---------------- zero-workspace fallback (round-1 kernel, known correct) ----------------
__global__ __launch_bounds__(512, 2)
void attn_fallback(const float* __restrict__ Qg0, const float* __restrict__ Kg0,
                   const float* __restrict__ Vg0, float* __restrict__ Og0) {
  __shared__ __align__(16) unsigned short Klds[NHEAD][32][72];
  __shared__ __align__(16) unsigned short Vlds[NHEAD][HEADD][40];
  __shared__ __align__(16) unsigned short EA2[NHEAD][64][40];
  const int tid = threadIdx.x, h = tid >> 6, lane = tid & 63, quad = lane >> 4, l15 = lane & 15;
  const int b = blockIdx.x >> 6, s0 = (blockIdx.x & 63) * 64;
  const float* Qg = Qg0 + ((size_t)(b * NHEAD + h)) * S_LEN * HEADD;
  const float* Kg = Kg0 + ((size_t)(b * NHEAD + h)) * HEADD * S_LEN;
  const float* Vg = Vg0 + ((size_t)(b * NHEAD + h)) * S_LEN * HEADD;
  float* Og = Og0 + ((size_t)(b * NHEAD + h)) * S_LEN * HEADD;
  const float SC = 0.04419417382415922f;
  short8 qf[4][2];
#pragma unroll
  for (int ss = 0; ss < 4; ++ss)
#pragma unroll
    for (int kk = 0; kk < 2; ++kk) {
      const float* p = Qg + (size_t)(s0 + ss * 16 + l15) * HEADD + kk * 32 + quad * 8;
      float4v a0 = *(const float4v*)p; float4v a1 = *(const float4v*)(p + 4);
      short8 f;
      f[0] = (short)f2bf(a0[0]); f[1] = (short)f2bf(a0[1]); f[2] = (short)f2bf(a0[2]); f[3] = (short)f2bf(a0[3]);
      f[4] = (short)f2bf(a1[0]); f[5] = (short)f2bf(a1[1]); f[6] = (short)f2bf(a1[2]); f[7] = (short)f2bf(a1[3]);
      qf[ss][kk] = f;
    }
  float4v acc[4][4];
#pragma unroll
  for (int ss = 0; ss < 4; ++ss)
#pragma unroll
    for (int ds = 0; ds < 4; ++ds) acc[ss][ds] = (float4v){0.f, 0.f, 0.f, 0.f};
  const int koct = lane >> 3, kt4 = (lane & 7) * 4, vdq = lane & 15, vtg = lane >> 4;
  const int s_sm = tid >> 3, t4_sm = (tid & 7) * 4;
  for (int it = 0; it < S_LEN / 32; ++it) {
    const int t0 = it * 32;
    {
      float buf[8][4];
#pragma unroll
      for (int j = 0; j < 8; ++j) {
        float4v v = *(const float4v*)(Kg + (size_t)(koct * 8 + j) * S_LEN + t0 + kt4);
        buf[j][0] = v[0]; buf[j][1] = v[1]; buf[j][2] = v[2]; buf[j][3] = v[3];
      }
#pragma unroll
      for (int c = 0; c < 4; ++c) {
        short8 f;
#pragma unroll
        for (int j = 0; j < 8; ++j) f[j] = (short)f2bf(buf[j][c]);
        *(short8*)&Klds[h][kt4 + c][koct * 8] = f;
      }
    }
    {
      float buf[8][4];
#pragma unroll
      for (int j = 0; j < 8; ++j) {
        float4v v = *(const float4v*)(Vg + (size_t)(t0 + vtg * 8 + j) * HEADD + vdq * 4);
        buf[j][0] = v[0]; buf[j][1] = v[1]; buf[j][2] = v[2]; buf[j][3] = v[3];
      }
#pragma unroll
      for (int c = 0; c < 4; ++c) {
        short8 f;
#pragma unroll
        for (int j = 0; j < 8; ++j) f[j] = (short)f2bf(buf[j][c]);
        *(short8*)&Vlds[h][vdq * 4 + c][vtg * 8] = f;
      }
    }
    __syncthreads();
#pragma unroll
    for (int ts = 0; ts < 2; ++ts) {
      short8 kf0 = *(const short8*)&Klds[h][ts * 16 + l15][quad * 8];
      short8 kf1 = *(const short8*)&Klds[h][ts * 16 + l15][32 + quad * 8];
#pragma unroll
      for (int ss = 0; ss < 4; ++ss) {
        float4v e = (float4v){0.f, 0.f, 0.f, 0.f};
        e = __builtin_amdgcn_mfma_f32_16x16x32_bf16(qf[ss][0], kf0, e, 0, 0, 0);
        e = __builtin_amdgcn_mfma_f32_16x16x32_bf16(qf[ss][1], kf1, e, 0, 0, 0);
#pragma unroll
        for (int r = 0; r < 4; ++r)
          EA2[h][ss * 16 + quad * 4 + r][ts * 16 + l15] = __half_as_ushort(__float2half(e[r] * SC));
      }
    }
    __syncthreads();
    {
      float ev[8][4];
#pragma unroll
      for (int hh = 0; hh < 8; ++hh) {
        unsigned long long u = *(const unsigned long long*)&EA2[hh][s_sm][t4_sm];
        ev[hh][0] = __half2float(__ushort_as_half((unsigned short)u));
        ev[hh][1] = __half2float(__ushort_as_half((unsigned short)(u >> 16)));
        ev[hh][2] = __half2float(__ushort_as_half((unsigned short)(u >> 32)));
        ev[hh][3] = __half2float(__ushort_as_half((unsigned short)(u >> 48)));
      }
#pragma unroll
      for (int c = 0; c < 4; ++c) {
        float m = ev[0][c];
#pragma unroll
        for (int hh = 1; hh < 8; ++hh) m = fmaxf(m, ev[hh][c]);
        float sum = 0.f;
#pragma unroll
        for (int hh = 0; hh < 8; ++hh) { float x = __expf(ev[hh][c] - m); ev[hh][c] = x; sum += x; }
        float inv = __builtin_amdgcn_rcpf(sum);
#pragma unroll
        for (int hh = 0; hh < 8; ++hh) ev[hh][c] *= inv;
      }
#pragma unroll
      for (int hh = 0; hh < 8; ++hh) {
        unsigned short u0 = f2bf(ev[hh][0]), u1 = f2bf(ev[hh][1]), u2 = f2bf(ev[hh][2]), u3 = f2bf(ev[hh][3]);
        unsigned long long w = (unsigned long long)u0 | ((unsigned long long)u1 << 16) |
                               ((unsigned long long)u2 << 32) | ((unsigned long long)u3 << 48);
        *(unsigned long long*)&EA2[hh][s_sm][t4_sm] = w;
      }
    }
    __syncthreads();
    {
      short8 af[4], vf[4];
#pragma unroll
      for (int ss = 0; ss < 4; ++ss) af[ss] = *(const short8*)&EA2[h][ss * 16 + l15][quad * 8];
#pragma unroll
      for (int ds = 0; ds < 4; ++ds) vf[ds] = *(const short8*)&Vlds[h][ds * 16 + l15][quad * 8];
#pragma unroll
      for (int ss = 0; ss < 4; ++ss)
#pragma unroll
        for (int ds = 0; ds < 4; ++ds)
          acc[ss][ds] = __builtin_amdgcn_mfma_f32_16x16x32_bf16(af[ss], vf[ds], acc[ss][ds], 0, 0, 0);
    }
    __syncthreads();
  }
#pragma unroll
  for (int ss = 0; ss < 4; ++ss)
#pragma unroll
    for (int ds = 0; ds < 4; ++ds)
#pragma unroll
      for (int r = 0; r < 4; ++r)
        Og[(size_t)(s0 + ss * 16 + quad * 4 + r) * HEADD + ds * 16 + l15] = acc[ss][ds][r];
}

extern "C" void kernel_launch(void* const* d_in, const int* in_sizes, int n_in,
                              void* d_out, int out_size, void* d_ws, size_t ws_size,
                              hipStream_t stream) {
  const float* Q = (const float*)d_in[0];
  const float* K = (const float*)d_in[1];
  const float* V = (const float*)d_in[2];
  float* O = (float*)d_out;

  if (ws_size >= WS_FULL) {
    unsigned short* Kt = (unsigned short*)d_ws;
    unsigned short* Vt = (unsigned short*)((char*)d_ws + VT_OFF);
    unsigned int* part = (unsigned int*)((char*)d_ws + PART_OFF);
    hipLaunchKernelGGL(prepass_cvt, dim3(1024), dim3(256), 0, stream, K, V, Kt, Vt);
    hipLaunchKernelGGL(attn_main, dim3(1024), dim3(512), 0, stream, Q, Kt, Vt, part);
    hipLaunchKernelGGL(reduce_partials, dim3(8192), dim3(256), 0, stream, part, O);
  } else {
    hipLaunchKernelGGL(attn_fallback, dim3(128), dim3(512), 0, stream, Q, K, V, O);
  }
}